// Round 1
// baseline (127.525 us; speedup 1.0000x reference)
//
#include <hip/hip_runtime.h>

#define T_LEN   1048576
#define NB      1024        // blocks
#define BLOCK   256         // threads per block
#define ITEMS   4           // elements per thread
#define CHUNK   (BLOCK*ITEMS)   // 1024 elements per block
#define MAXO    25
#define CLAMP_HI 24.0f

// Saturating-add function f(c) = min(max(c + a, l), h).
// Closed under composition; min applied LAST handles the l>h (fully
// saturated) case correctly.
struct Trip { float a, l, h; };

__device__ __forceinline__ Trip comb(const Trip& x, const Trip& y) {
    // apply x first, then y
    Trip r;
    r.a = x.a + y.a;
    r.l = fmaxf(x.l + y.a, y.l);
    r.h = fminf(fmaxf(x.h + y.a, y.l), y.h);
    return r;
}

__device__ __forceinline__ float applyT(const Trip& p, float c) {
    return fminf(fmaxf(c + p.a, p.l), p.h);
}

// ---------------- K1: per-block triple reduction ----------------
__global__ __launch_bounds__(BLOCK)
void k_reduce(const int* __restrict__ seq, const float* __restrict__ delta,
              float* __restrict__ wsf) {
    __shared__ float dl[16];
    __shared__ Trip sc[BLOCK];
    const int tid = threadIdx.x, bid = blockIdx.x;

    if (tid < 16) dl[tid] = delta[tid];
    __syncthreads();

    const int4 s4 = *(const int4*)(seq + bid * CHUNK + tid * ITEMS);
    const float d0 = dl[s4.x], d1 = dl[s4.y], d2 = dl[s4.z], d3 = dl[s4.w];

    Trip t = {d0, 0.0f, CLAMP_HI};
    { Trip e = {d1, 0.0f, CLAMP_HI}; t = comb(t, e); }
    { Trip e = {d2, 0.0f, CLAMP_HI}; t = comb(t, e); }
    { Trip e = {d3, 0.0f, CLAMP_HI}; t = comb(t, e); }
    sc[tid] = t;
    __syncthreads();

    // order-preserving adjacent-pair tree reduce (op is non-commutative)
    for (int s = 1; s < BLOCK; s <<= 1) {
        const int idx = tid * 2 * s;
        if (idx + s < BLOCK) sc[idx] = comb(sc[idx], sc[idx + s]);
        __syncthreads();
    }
    if (tid == 0) {
        wsf[3 * bid + 0] = sc[0].a;
        wsf[3 * bid + 1] = sc[0].l;
        wsf[3 * bid + 2] = sc[0].h;
    }
}

// ---------------- K2: entry-state + local scan + softmax write ----------------
__global__ __launch_bounds__(BLOCK)
void k_main(const int* __restrict__ seq, const float* __restrict__ delta,
            const float* __restrict__ bias, const float* __restrict__ scale,
            const float* __restrict__ wsf, float* __restrict__ out) {
    __shared__ float tri_raw[NB * 3];                       // 12 KB
    __shared__ Trip  sc[BLOCK];                             // 3 KB
    __shared__ float dl[16], bs[MAXO];
    __shared__ float c_arr[CHUNK], m_arr[CHUNK], r_arr[CHUNK]; // 12 KB
    __shared__ float centry;

    const int tid = threadIdx.x, bid = blockIdx.x;

    if (tid < 16)   dl[tid] = delta[tid];
    if (tid < MAXO) bs[tid] = bias[tid];
    const float sfac = scale[0];
    for (int i = tid; i < NB * 3; i += BLOCK) tri_raw[i] = wsf[i];
    __syncthreads();

    // ---- phase a: entry counter for this block (redundant per-block scan) ----
    const Trip* tr = (const Trip*)tri_raw;
    {
        Trip t = tr[4 * tid + 0];
        t = comb(t, tr[4 * tid + 1]);
        t = comb(t, tr[4 * tid + 2]);
        t = comb(t, tr[4 * tid + 3]);
        sc[tid] = t;
        __syncthreads();
        Trip val = t;
        for (int off = 1; off < BLOCK; off <<= 1) {
            Trip v = val;
            if (tid >= off) v = comb(sc[tid - off], val);
            __syncthreads();
            sc[tid] = v; val = v;
            __syncthreads();
        }
        if (tid == 0) {
            const int q = bid >> 2, r = bid & 3;
            Trip P; bool have = false;
            if (q > 0) { P = sc[q - 1]; have = true; }
            for (int j = 0; j < r; ++j) {
                const Trip e = tr[4 * q + j];
                P = have ? comb(P, e) : e;
                have = true;
            }
            centry = have ? applyT(P, 0.0f) : 0.0f;
        }
    }
    __syncthreads();

    // ---- phase b: per-thread fold of own 4 elements + block scan ----
    const int base = bid * CHUNK;
    const int4 s4 = *(const int4*)(seq + base + tid * ITEMS);
    const float d0 = dl[s4.x], d1 = dl[s4.y], d2 = dl[s4.z], d3 = dl[s4.w];

    Trip t = {d0, 0.0f, CLAMP_HI};
    { Trip e = {d1, 0.0f, CLAMP_HI}; t = comb(t, e); }
    { Trip e = {d2, 0.0f, CLAMP_HI}; t = comb(t, e); }
    { Trip e = {d3, 0.0f, CLAMP_HI}; t = comb(t, e); }
    sc[tid] = t;
    __syncthreads();
    {
        Trip val = t;
        for (int off = 1; off < BLOCK; off <<= 1) {
            Trip v = val;
            if (tid >= off) v = comb(sc[tid - off], val);
            __syncthreads();
            sc[tid] = v; val = v;
            __syncthreads();
        }
    }
    float c = (tid == 0) ? centry : applyT(sc[tid - 1], centry);

    // ---- phase c: sequential counters + per-row softmax stats ----
    const float ds[ITEMS] = {d0, d1, d2, d3};
#pragma unroll
    for (int e = 0; e < ITEMS; ++e) {
        c = fminf(fmaxf(c + ds[e], 0.0f), CLAMP_HI);
        float m = -1e30f;
#pragma unroll
        for (int j = 0; j < MAXO; ++j) {
            const float l = fmaf(-sfac, fabsf((float)j - c), bs[j]);
            m = fmaxf(m, l);
        }
        float sum = 0.0f;
#pragma unroll
        for (int j = 0; j < MAXO; ++j) {
            const float l = fmaf(-sfac, fabsf((float)j - c), bs[j]);
            sum += __expf(l - m);
        }
        const int row = tid * ITEMS + e;
        c_arr[row] = c;
        m_arr[row] = m;
        r_arr[row] = 1.0f / sum;
    }
    __syncthreads();

    // ---- phase d: coalesced softmax writes ----
    float* outp = out + (size_t)base * MAXO;
    const int TOT = CHUNK * MAXO; // 25600
#pragma unroll 4
    for (int i = tid; i < TOT; i += BLOCK) {
        const int trow = i / 25;          // magic-mul division
        const int j = i - trow * 25;
        const float cc = c_arr[trow];
        const float l = fmaf(-sfac, fabsf((float)j - cc), bs[j]);
        outp[i] = __expf(l - m_arr[trow]) * r_arr[trow];
    }
}

extern "C" void kernel_launch(void* const* d_in, const int* in_sizes, int n_in,
                              void* d_out, int out_size, void* d_ws, size_t ws_size,
                              hipStream_t stream) {
    const int*   seq   = (const int*)d_in[0];
    const float* delta = (const float*)d_in[1];
    const float* bias  = (const float*)d_in[2];
    const float* scale = (const float*)d_in[3];
    float* out = (float*)d_out;
    float* wsf = (float*)d_ws;   // needs NB*3*4 = 12 KB

    k_reduce<<<NB, BLOCK, 0, stream>>>(seq, delta, wsf);
    k_main  <<<NB, BLOCK, 0, stream>>>(seq, delta, bias, scale, wsf, out);
}

// Round 2
// 123.821 us; speedup vs baseline: 1.0299x; 1.0299x over previous
//
#include <hip/hip_runtime.h>

#define T_LEN   1048576
#define SEG     256                 // elements per segment / rows per K3 block
#define NSEG    (T_LEN / SEG)       // 4096
#define MAXO    25
#define CLAMP_HI 24.0f
#define BIGF    1e30f

// Saturating-add function f(c) = min(max(c + a, l), h); closed under composition.
struct Trip { float a, l, h; };

__device__ __forceinline__ Trip comb(Trip x, Trip y) {   // apply x first, then y
    Trip r;
    r.a = x.a + y.a;
    r.l = fmaxf(x.l + y.a, y.l);
    r.h = fminf(fmaxf(x.h + y.a, y.l), y.h);
    return r;
}
__device__ __forceinline__ float applyT(Trip p, float c) {
    return fminf(fmaxf(c + p.a, p.l), p.h);
}
__device__ __forceinline__ Trip shflUpTrip(Trip v, int off) {
    Trip r;
    r.a = __shfl_up(v.a, off, 64);
    r.l = __shfl_up(v.l, off, 64);
    r.h = __shfl_up(v.h, off, 64);
    return r;
}

// ---------------- K1: per-segment triple (1024 blocks, wave = 1 segment) ----
__global__ __launch_bounds__(256)
void k1_seg(const int* __restrict__ seq, const float* __restrict__ delta,
            float* __restrict__ tri) {
    __shared__ float dl[16];
    const int tid = threadIdx.x, lane = tid & 63;
    if (tid < 16) dl[tid] = delta[tid];
    __syncthreads();

    const int4 s4 = *(const int4*)(seq + blockIdx.x * 1024 + tid * 4);
    Trip t = {dl[s4.x], 0.0f, CLAMP_HI};
    { Trip e = {dl[s4.y], 0.0f, CLAMP_HI}; t = comb(t, e); }
    { Trip e = {dl[s4.z], 0.0f, CLAMP_HI}; t = comb(t, e); }
    { Trip e = {dl[s4.w], 0.0f, CLAMP_HI}; t = comb(t, e); }

#pragma unroll
    for (int off = 1; off < 64; off <<= 1) {
        Trip o = shflUpTrip(t, off);
        if (lane >= off) t = comb(o, t);
    }
    if (lane == 63) {
        const int sid = blockIdx.x * 4 + (tid >> 6);
        tri[3 * sid + 0] = t.a;
        tri[3 * sid + 1] = t.l;
        tri[3 * sid + 2] = t.h;
    }
}

// ---------------- K2: scan 4096 triples once -> per-segment entry counters --
__global__ __launch_bounds__(1024)
void k2_scan(const float* __restrict__ tri, float* __restrict__ entry) {
    __shared__ Trip agg[16];
    const int tid = threadIdx.x, lane = tid & 63, wid = tid >> 6;

    const float4* p = (const float4*)(tri + tid * 12);   // 4 triples = 48 B
    const float4 f0 = p[0], f1 = p[1], f2 = p[2];
    const Trip t0 = {f0.x, f0.y, f0.z};
    const Trip t1 = {f0.w, f1.x, f1.y};
    const Trip t2 = {f1.z, f1.w, f2.x};
    const Trip t3 = {f2.y, f2.z, f2.w};

    Trip incl = comb(comb(comb(t0, t1), t2), t3);
#pragma unroll
    for (int off = 1; off < 64; off <<= 1) {
        Trip o = shflUpTrip(incl, off);
        if (lane >= off) incl = comb(o, incl);
    }
    if (lane == 63) agg[wid] = incl;
    __syncthreads();

    Trip W = {0.0f, -BIGF, BIGF};                        // identity
    for (int w = 0; w < wid; ++w) W = comb(W, agg[w]);
    const Trip prev = shflUpTrip(incl, 1);
    const Trip E = (lane == 0) ? W : comb(W, prev);      // exclusive prefix

    float c = applyT(E, 0.0f);
    entry[4 * tid + 0] = c;
    c = applyT(t0, c); entry[4 * tid + 1] = c;
    c = applyT(t1, c); entry[4 * tid + 2] = c;
    c = applyT(t2, c); entry[4 * tid + 3] = c;
}

// ---------------- K3: per-row softmax, single exp pass, float4 writes -------
__global__ __launch_bounds__(256)
void k3_out(const int* __restrict__ seq, const float* __restrict__ delta,
            const float* __restrict__ bias, const float* __restrict__ scale,
            const float* __restrict__ entry, float* __restrict__ out) {
    __shared__ float tile[SEG * MAXO];                   // 25600 B
    __shared__ Trip agg[4];
    __shared__ float dl[16], bs[MAXO];

    const int tid = threadIdx.x, lane = tid & 63, wid = tid >> 6;
    const int bid = blockIdx.x;

    if (tid < 16)   dl[tid] = delta[tid];
    if (tid < MAXO) bs[tid] = bias[tid];
    const float sfac = scale[0];
    const float cseg = entry[bid];                       // broadcast load
    const int s = seq[bid * SEG + tid];
    __syncthreads();

    Trip t = {dl[s], 0.0f, CLAMP_HI};
#pragma unroll
    for (int off = 1; off < 64; off <<= 1) {
        Trip o = shflUpTrip(t, off);
        if (lane >= off) t = comb(o, t);
    }
    if (lane == 63) agg[wid] = t;
    __syncthreads();

    float cb = cseg;
    for (int w = 0; w < wid; ++w) cb = applyT(agg[w], cb);
    const float c = applyT(t, cb);                       // counter for row tid

    // softmax without max-subtraction (logits <= ~0.4, fp32 safe)
    float ev[MAXO];
    float sum = 0.0f;
#pragma unroll
    for (int j = 0; j < MAXO; ++j) {
        ev[j] = __expf(fmaf(-sfac, fabsf((float)j - c), bs[j]));
        sum += ev[j];
    }
    const float r = 1.0f / sum;
#pragma unroll
    for (int j = 0; j < MAXO; ++j)                       // stride-25: bank-conflict-free
        tile[tid * MAXO + j] = ev[j] * r;
    __syncthreads();

    const float4* tp = (const float4*)tile;
    float4* op = (float4*)(out + (size_t)bid * SEG * MAXO);
#pragma unroll
    for (int i = tid; i < SEG * MAXO / 4; i += 256)      // 1600 float4s
        op[i] = tp[i];
}

extern "C" void kernel_launch(void* const* d_in, const int* in_sizes, int n_in,
                              void* d_out, int out_size, void* d_ws, size_t ws_size,
                              hipStream_t stream) {
    const int*   seq   = (const int*)d_in[0];
    const float* delta = (const float*)d_in[1];
    const float* bias  = (const float*)d_in[2];
    const float* scale = (const float*)d_in[3];
    float* out = (float*)d_out;

    float* tri   = (float*)d_ws;                 // NSEG*3 floats = 48 KB
    float* entry = tri + NSEG * 3;               // NSEG floats   = 16 KB

    k1_seg <<<T_LEN / 1024, 256, 0, stream>>>(seq, delta, tri);
    k2_scan<<<1, 1024, 0, stream>>>(tri, entry);
    k3_out <<<NSEG, 256, 0, stream>>>(seq, delta, bias, scale, entry, out);
}